// Round 5
// baseline (476.545 us; speedup 1.0000x reference)
//
#include <hip/hip_runtime.h>

#define NC 19
#define EPS 1e-5f
typedef unsigned long long u64;

// D = popcount(S0) + D, forced onto the VALU pipe (v_bcnt_u32_b32).
// S0 is a wave-uniform SGPR (ballot word); acc is a per-lane VGPR.
__device__ __forceinline__ void bcnt_acc(unsigned& acc, unsigned word) {
    asm("v_bcnt_u32_b32 %0, %1, %0" : "+v"(acc) : "s"(word));
}

// One ballot round: 64 elements (one per lane).
// VALU: 38 v_cmp + 76 v_bcnt; SALU: 19 s_and_b64 + 19 s_bcnt1 + 19 s_add.
__device__ __forceinline__ void round64(int t, int p,
                                        unsigned* __restrict__ tc,
                                        unsigned* __restrict__ pc,
                                        unsigned* __restrict__ qc)
{
    #pragma unroll
    for (int c = 0; c < NC; ++c) {
        u64 tm = __ballot(t == c);
        u64 pm = __ballot(p == c);
        bcnt_acc(tc[c], (unsigned)tm);
        bcnt_acc(tc[c], (unsigned)(tm >> 32));
        bcnt_acc(pc[c], (unsigned)pm);
        bcnt_acc(pc[c], (unsigned)(pm >> 32));
        qc[c] += (unsigned)__popcll(tm & pm);   // uniform -> SALU
    }
}

__global__ __launch_bounds__(256) void dice_main(
    const int4* __restrict__ yp, const int4* __restrict__ yt,
    unsigned* __restrict__ gU, unsigned* __restrict__ gI,
    unsigned* __restrict__ ticket, float* __restrict__ out, int n4)
{
    // tc/pc: per-lane VGPR accumulators (wave-uniform values); qc: SGPR.
    unsigned tc[NC], pc[NC], qc[NC];
    #pragma unroll
    for (int c = 0; c < NC; ++c) { tc[c] = 0u; pc[c] = 0u; qc[c] = 0u; }

    const int stride = gridDim.x * 256;
    for (int i = blockIdx.x * 256 + threadIdx.x; i < n4; i += stride) {
        int4 tv = yt[i];
        int4 pv = yp[i];
        round64(tv.x, pv.x, tc, pc, qc);
        round64(tv.y, pv.y, tc, pc, qc);
        round64(tv.z, pv.z, tc, pc, qc);
        round64(tv.w, pv.w, tc, pc, qc);
    }

    // ---- epilogue: per-wave counts are already wave-reduced (uniform) ----
    __shared__ u64 ldsUI[4 * NC];   // per wave: U (lo 32) | I (hi 32)
    __shared__ unsigned s_old;
    const int lane = threadIdx.x & 63;
    const int wv   = threadIdx.x >> 6;

    if (lane == 0) {
        #pragma unroll
        for (int c = 0; c < NC; ++c) {
            unsigned U = tc[c] + pc[c];          // count_y + count_p
            ldsUI[wv * NC + c] = (u64)U | ((u64)qc[c] << 32);
        }
    }
    __syncthreads();

    if (threadIdx.x < NC) {
        unsigned U = 0, I = 0;
        #pragma unroll
        for (int w = 0; w < 4; ++w) {
            u64 v = ldsUI[w * NC + threadIdx.x];
            U += (unsigned)v;
            I += (unsigned)(v >> 32);
        }
        atomicAdd(&gU[threadIdx.x], U);
        atomicAdd(&gI[threadIdx.x], I);
    }

    // ---- last-block fused finalization (verified R2-R4) ----
    __threadfence();
    __syncthreads();
    if (threadIdx.x == 0)
        s_old = __hip_atomic_fetch_add(ticket, 1u, __ATOMIC_ACQ_REL, __HIP_MEMORY_SCOPE_AGENT);
    __syncthreads();
    if (s_old == gridDim.x - 1 && threadIdx.x < 64) {
        float dice = 0.0f;
        if (lane < NC) {
            unsigned Uv = __hip_atomic_load(&gU[lane], __ATOMIC_RELAXED, __HIP_MEMORY_SCOPE_AGENT);
            unsigned Iv = __hip_atomic_load(&gI[lane], __ATOMIC_RELAXED, __HIP_MEMORY_SCOPE_AGENT);
            float I = (float)Iv;
            float U = (float)Uv;          // union = U - I
            dice = (2.0f * I + EPS) / ((U - I) + EPS);
        }
        #pragma unroll
        for (int off = 32; off > 0; off >>= 1)
            dice += __shfl_down(dice, off, 64);
        if (lane == 0) out[0] = 1.0f - dice * (1.0f / (float)NC);
    }
}

extern "C" void kernel_launch(void* const* d_in, const int* in_sizes, int n_in,
                              void* d_out, int out_size, void* d_ws, size_t ws_size,
                              hipStream_t stream)
{
    const int4* yp = (const int4*)d_in[0];   // y_pred, int32
    const int4* yt = (const int4*)d_in[1];   // y,      int32
    unsigned* gU     = (unsigned*)d_ws;      // 19 u32: count_y + count_p
    unsigned* gI     = gU + NC;              // 19 u32: intersection
    unsigned* ticket = gI + NC;              // 1 u32
    float* out = (float*)d_out;

    const int n  = in_sizes[0];              // 16*1024*1024
    const int n4 = n >> 2;

    hipMemsetAsync(d_ws, 0, (2 * NC + 1) * sizeof(unsigned), stream);

    // grid 2048: 8 int4 per thread; high wave count so VALU (v_cmp+v_bcnt)
    // and SALU (s_and+s_bcnt1+s_add) streams from different waves co-issue.
    dice_main<<<2048, 256, 0, stream>>>(yp, yt, gU, gI, ticket, out, n4);
}

// Round 6
// 433.074 us; speedup vs baseline: 1.1004x; 1.1004x over previous
//
#include <hip/hip_runtime.h>

#define NC 19
#define NB (NC * NC)     // 361 joint-histogram bins
#define NCOPY 8          // one private copy per HALF-wave (32 lanes)
#define EPS 1e-5f

// Joint histogram J[t*19+p]; row sums = count_y, col sums = count_p,
// diagonal = intersection. One LDS atomic per element — measured best
// primitive (R1: 52us; all VALU-indicator schemes 170-394us, R2-R5).
__global__ __launch_bounds__(256, 8) void dice_main(
    const int4* __restrict__ yp, const int4* __restrict__ yt,
    unsigned* __restrict__ gJ, unsigned* __restrict__ ticket,
    float* __restrict__ out, int n4)
{
    __shared__ unsigned sJ[NCOPY * NB];   // 11.6 KB
    __shared__ unsigned s_old;
    const int tid = threadIdx.x;
    unsigned* mine = &sJ[(tid >> 5) * NB];  // half-wave private copy

    for (int i = tid; i < NCOPY * NB; i += 256) sJ[i] = 0u;
    __syncthreads();

    const int stride = gridDim.x * 256;
    int i = blockIdx.x * 256 + tid;

    // 2-deep load batching: both iterations' loads issue before the atomics.
    while (i + stride < n4) {
        int4 t0 = yt[i];          int4 p0 = yp[i];
        int4 t1 = yt[i + stride]; int4 p1 = yp[i + stride];
        atomicAdd(&mine[t0.x * NC + p0.x], 1u);
        atomicAdd(&mine[t0.y * NC + p0.y], 1u);
        atomicAdd(&mine[t0.z * NC + p0.z], 1u);
        atomicAdd(&mine[t0.w * NC + p0.w], 1u);
        atomicAdd(&mine[t1.x * NC + p1.x], 1u);
        atomicAdd(&mine[t1.y * NC + p1.y], 1u);
        atomicAdd(&mine[t1.z * NC + p1.z], 1u);
        atomicAdd(&mine[t1.w * NC + p1.w], 1u);
        i += 2 * stride;
    }
    if (i < n4) {
        int4 t0 = yt[i]; int4 p0 = yp[i];
        atomicAdd(&mine[t0.x * NC + p0.x], 1u);
        atomicAdd(&mine[t0.y * NC + p0.y], 1u);
        atomicAdd(&mine[t0.z * NC + p0.z], 1u);
        atomicAdd(&mine[t0.w * NC + p0.w], 1u);
    }
    __syncthreads();

    // Merge 8 copies -> one device atomic per bin per block.
    for (int b = tid; b < NB; b += 256) {
        unsigned v = 0;
        #pragma unroll
        for (int c = 0; c < NCOPY; ++c) v += sJ[c * NB + b];
        if (v) atomicAdd(&gJ[b], v);
    }

    // ---- last-block fused finalization (absmax-0-verified pattern) ----
    __threadfence();
    __syncthreads();
    if (tid == 0)
        s_old = __hip_atomic_fetch_add(ticket, 1u, __ATOMIC_ACQ_REL, __HIP_MEMORY_SCOPE_AGENT);
    __syncthreads();
    if (s_old == gridDim.x - 1 && tid < 64) {
        const int lane = tid;
        float dice = 0.0f;
        if (lane < NC) {
            float inter = 0.0f, cy = 0.0f, cp = 0.0f;
            #pragma unroll
            for (int j = 0; j < NC; ++j) {
                unsigned r = __hip_atomic_load(&gJ[lane * NC + j], __ATOMIC_RELAXED, __HIP_MEMORY_SCOPE_AGENT);
                unsigned c = __hip_atomic_load(&gJ[j * NC + lane], __ATOMIC_RELAXED, __HIP_MEMORY_SCOPE_AGENT);
                cy += (float)r;
                cp += (float)c;
                if (j == lane) inter = (float)r;
            }
            float uni = cy + cp - inter;
            dice = (2.0f * inter + EPS) / (uni + EPS);
        }
        #pragma unroll
        for (int off = 32; off > 0; off >>= 1)
            dice += __shfl_down(dice, off, 64);
        if (lane == 0) out[0] = 1.0f - dice * (1.0f / (float)NC);
    }
}

extern "C" void kernel_launch(void* const* d_in, const int* in_sizes, int n_in,
                              void* d_out, int out_size, void* d_ws, size_t ws_size,
                              hipStream_t stream)
{
    const int4* yp = (const int4*)d_in[0];   // y_pred, int32
    const int4* yt = (const int4*)d_in[1];   // y,      int32
    unsigned* gJ     = (unsigned*)d_ws;      // 361 u32 joint histogram
    unsigned* ticket = gJ + NB;              // 1 u32
    float* out = (float*)d_out;

    const int n  = in_sizes[0];              // 16*1024*1024
    const int n4 = n >> 2;

    hipMemsetAsync(d_ws, 0, (NB + 1) * sizeof(unsigned), stream);

    // grid 2048: 8 blocks/CU -> 32 waves/CU (occupancy cap); exactly 8
    // int4-iterations per thread. LDS 11.6KB/block * 8 = 93KB/CU < 160KB.
    dice_main<<<2048, 256, 0, stream>>>(yp, yt, gJ, ticket, out, n4);
}